// Round 1
// baseline (256.246 us; speedup 1.0000x reference)
//
#include <hip/hip_runtime.h>

// Head: single-head causal attention. B=4, T=2048, D=1024, H=64. fp32 in/out.
// Strategy: bf16 MFMA for all matmuls (threshold 7.9e-2 permits), flash-style
// attention (no T×T materialization).
//
// ws layout (bytes):
//   [0,        393216)  Wt  bf16 [192][1024]  (transposed Wq|Wk|Wv, K-contiguous)
//   [393216,  1441792)  q   bf16 [8192][64]
//   [1441792, 2490368)  k   bf16 [8192][64]
//   [2490368, 3538944)  vT  bf16 [4][64][2048] (v transposed per batch)

typedef __attribute__((ext_vector_type(8))) __bf16 bf16x8;
typedef __attribute__((ext_vector_type(4))) float floatx4;

union BF8 {
    bf16x8 v;
    unsigned short s[8];
    uint4 u;
};

__device__ inline unsigned short f2bf(float f) {
    // round-to-nearest-even fp32 -> bf16 (inputs are finite; no NaN handling)
    unsigned int u = __float_as_uint(f);
    unsigned int r = (u + 0x7fffu + ((u >> 16) & 1u)) >> 16;
    return (unsigned short)r;
}

// ---------------------------------------------------------------------------
// Kernel 0: Wt[n][kk] = bf16(W_{n/64}[kk][n%64]);  n in [0,192), kk in [0,1024)
// Reads coalesced (h fastest); writes scattered 2B (tiny: 384 KB total).
// ---------------------------------------------------------------------------
__global__ __launch_bounds__(256) void wt_kernel(const float* __restrict__ Wq,
                                                 const float* __restrict__ Wk,
                                                 const float* __restrict__ Wv,
                                                 unsigned short* __restrict__ wt) {
    int idx = blockIdx.x * 256 + threadIdx.x;  // 196608 total
    int kk = idx / 192;
    int n = idx - kk * 192;
    int sel = n >> 6;
    int h = n & 63;
    const float* W = (sel == 0) ? Wq : (sel == 1) ? Wk : Wv;
    wt[(size_t)n * 1024 + kk] = f2bf(W[(size_t)kk * 64 + h]);
}

// ---------------------------------------------------------------------------
// Kernel 1: fused QKV projection. x[8192][1024] fp32 @ Wt -> q,k (bf16 [t][h])
// and vT (bf16 [b][h][t]). 128 blocks x 256 thr; wave = 16 rows x 192 cols.
// mfma_f32_16x16x32_bf16: A m=lane&15,k=quad*8+j ; B n=lane&15,k=quad*8+j ;
// C/D col=lane&15, row=quad*4+reg  (verified layouts per guide §3).
// ---------------------------------------------------------------------------
__global__ __launch_bounds__(256) void qkv_kernel(const float* __restrict__ x,
                                                  const unsigned short* __restrict__ wt,
                                                  unsigned short* __restrict__ qo,
                                                  unsigned short* __restrict__ ko,
                                                  unsigned short* __restrict__ vo) {
    const int tid = threadIdx.x;
    const int w = tid >> 6;
    const int lane = tid & 63;
    const int quad = lane >> 4;
    const int l16 = lane & 15;
    const int m0 = blockIdx.x * 64 + w * 16;  // wave's first row of x

    floatx4 acc[12];
#pragma unroll
    for (int i = 0; i < 12; ++i) acc[i] = (floatx4)(0.0f);

    const float* xp = x + (size_t)(m0 + l16) * 1024 + quad * 8;
    const unsigned short* wp = wt + (size_t)l16 * 1024 + quad * 8;

    for (int ks = 0; ks < 32; ++ks) {
        float4 a0 = *(const float4*)(xp + ks * 32);
        float4 a1 = *(const float4*)(xp + ks * 32 + 4);
        BF8 af;
        af.s[0] = f2bf(a0.x); af.s[1] = f2bf(a0.y);
        af.s[2] = f2bf(a0.z); af.s[3] = f2bf(a0.w);
        af.s[4] = f2bf(a1.x); af.s[5] = f2bf(a1.y);
        af.s[6] = f2bf(a1.z); af.s[7] = f2bf(a1.w);
#pragma unroll
        for (int nt = 0; nt < 12; ++nt) {
            BF8 bf_;
            bf_.u = *(const uint4*)(wp + (size_t)nt * 16 * 1024 + ks * 32);
            acc[nt] = __builtin_amdgcn_mfma_f32_16x16x32_bf16(af.v, bf_.v, acc[nt], 0, 0, 0);
        }
    }

    const int row0 = m0 + quad * 4;
#pragma unroll
    for (int nt = 0; nt < 4; ++nt)
#pragma unroll
        for (int r = 0; r < 4; ++r) {
            qo[(size_t)(row0 + r) * 64 + nt * 16 + l16] = f2bf(acc[nt][r]);
            ko[(size_t)(row0 + r) * 64 + nt * 16 + l16] = f2bf(acc[4 + nt][r]);
        }
    // v stored transposed: vT[b][h][t]; block never straddles a batch (2048%64==0)
    const int b = m0 >> 11;
    const int tloc = (m0 & 2047) + quad * 4;
#pragma unroll
    for (int nt = 0; nt < 4; ++nt)
#pragma unroll
        for (int r = 0; r < 4; ++r)
            vo[(size_t)(b * 64 + nt * 16 + l16) * 2048 + tloc + r] = f2bf(acc[8 + nt][r]);
}

// ---------------------------------------------------------------------------
// Kernel 2: flash causal attention. Grid = B * (T/64) = 128 blocks, 256 thr.
// Wave owns 16 q-rows. K-tiles of 64, only q0/64+1 tiles (causal), only the
// diagonal tile masked. Online softmax state per quad (rows quad*4+reg),
// reduced across the 16 lanes of the quad via shfl_xor 1/2/4/8.
// P goes C-layout -> LDS (stride 72 bf16, conflict-light, 16B-aligned rows)
// -> A-layout reads for PV.
// ---------------------------------------------------------------------------
__global__ __launch_bounds__(256) void attn_kernel(const unsigned short* __restrict__ qi,
                                                   const unsigned short* __restrict__ ki,
                                                   const unsigned short* __restrict__ vT,
                                                   float* __restrict__ out) {
    __shared__ __align__(16) unsigned short lds_p[4 * 16 * 72];
    const int tid = threadIdx.x;
    const int w = tid >> 6;
    const int lane = tid & 63;
    const int quad = lane >> 4;
    const int l16 = lane & 15;
    const int b = blockIdx.x >> 5;
    const int q0 = (blockIdx.x & 31) * 64;

    BF8 aq[2];
    {
        const unsigned short* qp = qi + (size_t)(b * 2048 + q0 + w * 16 + l16) * 64 + quad * 8;
        aq[0].u = *(const uint4*)(qp);
        aq[1].u = *(const uint4*)(qp + 32);
    }

    floatx4 oacc[4];
#pragma unroll
    for (int nt = 0; nt < 4; ++nt) oacc[nt] = (floatx4)(0.0f);
    float m_i[4], l_i[4];
#pragma unroll
    for (int r = 0; r < 4; ++r) { m_i[r] = -3.0e38f; l_i[r] = 0.0f; }

    unsigned short* myp = lds_p + w * (16 * 72);
    const int ntiles = (q0 >> 6) + 1;

    for (int jt = 0; jt < ntiles; ++jt) {
        const int j0 = jt * 64;

        // S = Q K^T for this 64x64 tile (wave: rows 16, cols 64)
        floatx4 s[4];
#pragma unroll
        for (int nt = 0; nt < 4; ++nt) s[nt] = (floatx4)(0.0f);
#pragma unroll
        for (int kst = 0; kst < 2; ++kst) {
#pragma unroll
            for (int nt = 0; nt < 4; ++nt) {
                BF8 bk;
                bk.u = *(const uint4*)(ki + (size_t)(b * 2048 + j0 + nt * 16 + l16) * 64 +
                                       kst * 32 + quad * 8);
                s[nt] = __builtin_amdgcn_mfma_f32_16x16x32_bf16(aq[kst].v, bk.v, s[nt], 0, 0, 0);
            }
        }

        // scale + causal mask (only diagonal tile)
        float sv[4][4];
        const bool diag = (jt == ntiles - 1);
#pragma unroll
        for (int nt = 0; nt < 4; ++nt)
#pragma unroll
            for (int r = 0; r < 4; ++r) {
                float val = s[nt][r] * 0.125f;
                if (diag) {
                    int key = j0 + nt * 16 + l16;
                    int qr = q0 + w * 16 + quad * 4 + r;
                    if (key > qr) val = -3.0e38f;
                }
                sv[nt][r] = val;
            }

        // online softmax: row max / alpha
        float alpha[4];
#pragma unroll
        for (int r = 0; r < 4; ++r) {
            float mx = fmaxf(fmaxf(sv[0][r], sv[1][r]), fmaxf(sv[2][r], sv[3][r]));
            mx = fmaxf(mx, __shfl_xor(mx, 1));
            mx = fmaxf(mx, __shfl_xor(mx, 2));
            mx = fmaxf(mx, __shfl_xor(mx, 4));
            mx = fmaxf(mx, __shfl_xor(mx, 8));
            float mn = fmaxf(m_i[r], mx);
            alpha[r] = __expf(m_i[r] - mn);
            m_i[r] = mn;
        }
        // P = exp(S - m), row sums
        float rs[4] = {0.f, 0.f, 0.f, 0.f};
#pragma unroll
        for (int nt = 0; nt < 4; ++nt)
#pragma unroll
            for (int r = 0; r < 4; ++r) {
                float p = __expf(sv[nt][r] - m_i[r]);
                sv[nt][r] = p;
                rs[r] += p;
            }
#pragma unroll
        for (int r = 0; r < 4; ++r) {
            float t = rs[r];
            t += __shfl_xor(t, 1);
            t += __shfl_xor(t, 2);
            t += __shfl_xor(t, 4);
            t += __shfl_xor(t, 8);
            l_i[r] = l_i[r] * alpha[r] + t;
        }
#pragma unroll
        for (int nt = 0; nt < 4; ++nt)
#pragma unroll
            for (int r = 0; r < 4; ++r) oacc[nt][r] *= alpha[r];

        // P: C-layout regs -> LDS (bf16) ; per-wave private region, in-wave
        // DS ordering guarantees write->read consistency without a barrier.
#pragma unroll
        for (int nt = 0; nt < 4; ++nt)
#pragma unroll
            for (int r = 0; r < 4; ++r)
                myp[(quad * 4 + r) * 72 + nt * 16 + l16] = f2bf(sv[nt][r]);

        // O += P @ V  (A-frag of P from LDS; B-frag of V contiguous via vT)
#pragma unroll
        for (int kst = 0; kst < 2; ++kst) {
            BF8 ap;
            ap.u = *(const uint4*)(myp + l16 * 72 + kst * 32 + quad * 8);
#pragma unroll
            for (int nt = 0; nt < 4; ++nt) {
                BF8 bv;
                bv.u = *(const uint4*)(vT + (size_t)(b * 64 + nt * 16 + l16) * 2048 + j0 +
                                       kst * 32 + quad * 8);
                oacc[nt] = __builtin_amdgcn_mfma_f32_16x16x32_bf16(ap.v, bv.v, oacc[nt], 0, 0, 0);
            }
        }
    }

    // epilogue: out = O / l
#pragma unroll
    for (int nt = 0; nt < 4; ++nt)
#pragma unroll
        for (int r = 0; r < 4; ++r)
            out[(size_t)(b * 2048 + q0 + w * 16 + quad * 4 + r) * 64 + nt * 16 + l16] =
                oacc[nt][r] / l_i[r];
}

extern "C" void kernel_launch(void* const* d_in, const int* in_sizes, int n_in,
                              void* d_out, int out_size, void* d_ws, size_t ws_size,
                              hipStream_t stream) {
    const float* x = (const float*)d_in[0];
    const float* Wq = (const float*)d_in[1];
    const float* Wk = (const float*)d_in[2];
    const float* Wv = (const float*)d_in[3];
    float* out = (float*)d_out;

    char* ws = (char*)d_ws;
    unsigned short* wt = (unsigned short*)(ws);
    unsigned short* q = (unsigned short*)(ws + 393216);
    unsigned short* k = (unsigned short*)(ws + 1441792);
    unsigned short* vT = (unsigned short*)(ws + 2490368);

    hipLaunchKernelGGL(wt_kernel, dim3(768), dim3(256), 0, stream, Wq, Wk, Wv, wt);
    hipLaunchKernelGGL(qkv_kernel, dim3(128), dim3(256), 0, stream, x, wt, q, k, vT);
    hipLaunchKernelGGL(attn_kernel, dim3(128), dim3(256), 0, stream, q, k, vT, out);
}

// Round 2
// 157.490 us; speedup vs baseline: 1.6271x; 1.6271x over previous
//
#include <hip/hip_runtime.h>

// Head: single-head causal attention. B=4, T=2048, D=1024, H=64. fp32 in/out.
// R2: fix latency-bound starvation.
//  - qkv: 512 blocks x 4 waves, wave = 16 rows x 48 cols (2048 waves, was 512).
//  - attn: split-K flash. Pass A: task=(b, q-tile16, key-chunk256), 2304 active
//    waves, <=4 K-tiles each (was: 512 waves, critical path 32 tiles).
//    Pass B: log-sum-exp merge of <=8 partials per q-tile.
//
// ws layout (bytes):
//   [0,        393216)   Wt  bf16 [192][1024]
//   [393216,  1441792)   q   bf16 [8192][64]
//   [1441792, 2490368)   k   bf16 [8192][64]
//   [2490368, 3538944)   vT  bf16 [4][64][2048]
//   [3538944, 20316160)  Opart fp32 [4096][16][64]   (id = b*1024+qt*8+kc)
//   [20316160,20578304)  mpart fp32 [4096][16]
//   [20578304,20840448)  lpart fp32 [4096][16]

typedef __attribute__((ext_vector_type(8))) __bf16 bf16x8;
typedef __attribute__((ext_vector_type(4))) float floatx4;

union BF8 {
    bf16x8 v;
    unsigned short s[8];
    uint4 u;
};

__device__ inline unsigned short f2bf(float f) {
    unsigned int u = __float_as_uint(f);
    unsigned int r = (u + 0x7fffu + ((u >> 16) & 1u)) >> 16;
    return (unsigned short)r;
}

// ---------------------------------------------------------------------------
// Kernel 0: Wt[n][kk] = bf16(W_{n/64}[kk][n%64])
// ---------------------------------------------------------------------------
__global__ __launch_bounds__(256) void wt_kernel(const float* __restrict__ Wq,
                                                 const float* __restrict__ Wk,
                                                 const float* __restrict__ Wv,
                                                 unsigned short* __restrict__ wt) {
    int idx = blockIdx.x * 256 + threadIdx.x;
    int kk = idx / 192;
    int n = idx - kk * 192;
    int sel = n >> 6;
    int h = n & 63;
    const float* W = (sel == 0) ? Wq : (sel == 1) ? Wk : Wv;
    wt[(size_t)n * 1024 + kk] = f2bf(W[(size_t)kk * 64 + h]);
}

// ---------------------------------------------------------------------------
// Kernel 1: QKV projection. 512 blocks x 256 thr. Block = 16 rows; wave w =
// those 16 rows x cols [w*48, w*48+48). 2048 waves total. A-frags straight
// from global (4x in-block redundancy -> L1/L2, same CU). 3 accs/wave.
// ---------------------------------------------------------------------------
__global__ __launch_bounds__(256) void qkv_kernel(const float* __restrict__ x,
                                                  const unsigned short* __restrict__ wt,
                                                  unsigned short* __restrict__ qo,
                                                  unsigned short* __restrict__ ko,
                                                  unsigned short* __restrict__ vo) {
    const int tid = threadIdx.x;
    const int w = tid >> 6;
    const int lane = tid & 63;
    const int quad = lane >> 4;
    const int l16 = lane & 15;
    const int m0 = blockIdx.x * 16;

    floatx4 acc[3];
#pragma unroll
    for (int i = 0; i < 3; ++i) acc[i] = (floatx4)(0.0f);

    const float* xp = x + (size_t)(m0 + l16) * 1024 + quad * 8;
    const unsigned short* wp = wt + (size_t)(w * 48 + l16) * 1024 + quad * 8;

    for (int ks = 0; ks < 32; ++ks) {
        float4 a0 = *(const float4*)(xp + ks * 32);
        float4 a1 = *(const float4*)(xp + ks * 32 + 4);
        BF8 af;
        af.s[0] = f2bf(a0.x); af.s[1] = f2bf(a0.y);
        af.s[2] = f2bf(a0.z); af.s[3] = f2bf(a0.w);
        af.s[4] = f2bf(a1.x); af.s[5] = f2bf(a1.y);
        af.s[6] = f2bf(a1.z); af.s[7] = f2bf(a1.w);
#pragma unroll
        for (int nt = 0; nt < 3; ++nt) {
            BF8 bf_;
            bf_.u = *(const uint4*)(wp + (size_t)nt * 16 * 1024 + ks * 32);
            acc[nt] = __builtin_amdgcn_mfma_f32_16x16x32_bf16(af.v, bf_.v, acc[nt], 0, 0, 0);
        }
    }

    const int row0 = m0 + quad * 4;
    const int b = m0 >> 11;  // block of 16 rows never straddles a batch
#pragma unroll
    for (int nt = 0; nt < 3; ++nt) {
        const int j = w * 3 + nt;       // 0..11, wave-uniform
        const int sel = j >> 2;
        const int h = (j & 3) * 16 + l16;
#pragma unroll
        for (int r = 0; r < 4; ++r) {
            unsigned short val = f2bf(acc[nt][r]);
            int row = row0 + r;
            if (sel == 0)
                qo[(size_t)row * 64 + h] = val;
            else if (sel == 1)
                ko[(size_t)row * 64 + h] = val;
            else
                vo[(size_t)(b * 64 + h) * 2048 + (row & 2047)] = val;
        }
    }
}

// ---------------------------------------------------------------------------
// Kernel 2: split-K flash pass A. Grid 1024 blocks x 256 thr; wave task
// id = blockIdx*4 + w in [0,4096): b=id>>10, qt=(id>>3)&127, kc=id&7.
// Active iff kc <= qt/16. Wave: 16 q-rows [qt*16..), keys [kc*256, kc*256+256)
// clipped causally; <=4 K-tiles of 64, only diagonal-overlap tiles masked.
// Writes unnormalized (m, l, O) partials.
// ---------------------------------------------------------------------------
__global__ __launch_bounds__(256) void attn_partial(const unsigned short* __restrict__ qi,
                                                    const unsigned short* __restrict__ ki,
                                                    const unsigned short* __restrict__ vT,
                                                    float* __restrict__ Opart,
                                                    float* __restrict__ mpart,
                                                    float* __restrict__ lpart) {
    __shared__ __align__(16) unsigned short lds_p[4 * 16 * 72];
    const int tid = threadIdx.x;
    const int w = tid >> 6;
    const int lane = tid & 63;
    const int quad = lane >> 4;
    const int l16 = lane & 15;
    const int id = blockIdx.x * 4 + w;
    const int b = id >> 10;
    const int qt = (id >> 3) & 127;
    const int kc = id & 7;
    if (kc > (qt >> 4)) return;
    const int r0 = qt * 16;

    BF8 aq[2];
    {
        const unsigned short* qp = qi + (size_t)(b * 2048 + r0 + l16) * 64 + quad * 8;
        aq[0].u = *(const uint4*)(qp);
        aq[1].u = *(const uint4*)(qp + 32);
    }

    floatx4 oacc[4];
#pragma unroll
    for (int nt = 0; nt < 4; ++nt) oacc[nt] = (floatx4)(0.0f);
    float m_i[4], l_i[4];
#pragma unroll
    for (int r = 0; r < 4; ++r) { m_i[r] = -3.0e38f; l_i[r] = 0.0f; }

    unsigned short* myp = lds_p + w * (16 * 72);

    for (int t = 0; t < 4; ++t) {
        const int j0 = kc * 256 + t * 64;
        if (j0 > r0 + 15) break;

        floatx4 s[4];
#pragma unroll
        for (int nt = 0; nt < 4; ++nt) s[nt] = (floatx4)(0.0f);
#pragma unroll
        for (int kst = 0; kst < 2; ++kst) {
#pragma unroll
            for (int nt = 0; nt < 4; ++nt) {
                BF8 bk;
                bk.u = *(const uint4*)(ki + (size_t)(b * 2048 + j0 + nt * 16 + l16) * 64 +
                                       kst * 32 + quad * 8);
                s[nt] = __builtin_amdgcn_mfma_f32_16x16x32_bf16(aq[kst].v, bk.v, s[nt], 0, 0, 0);
            }
        }

        float sv[4][4];
        const bool masked = (j0 + 63 > r0);
#pragma unroll
        for (int nt = 0; nt < 4; ++nt)
#pragma unroll
            for (int r = 0; r < 4; ++r) {
                float val = s[nt][r] * 0.125f;
                if (masked) {
                    int key = j0 + nt * 16 + l16;
                    int qr = r0 + quad * 4 + r;
                    if (key > qr) val = -3.0e38f;
                }
                sv[nt][r] = val;
            }

        float alpha[4];
#pragma unroll
        for (int r = 0; r < 4; ++r) {
            float mx = fmaxf(fmaxf(sv[0][r], sv[1][r]), fmaxf(sv[2][r], sv[3][r]));
            mx = fmaxf(mx, __shfl_xor(mx, 1));
            mx = fmaxf(mx, __shfl_xor(mx, 2));
            mx = fmaxf(mx, __shfl_xor(mx, 4));
            mx = fmaxf(mx, __shfl_xor(mx, 8));
            float mn = fmaxf(m_i[r], mx);
            alpha[r] = __expf(m_i[r] - mn);
            m_i[r] = mn;
        }
        float rs[4] = {0.f, 0.f, 0.f, 0.f};
#pragma unroll
        for (int nt = 0; nt < 4; ++nt)
#pragma unroll
            for (int r = 0; r < 4; ++r) {
                float p = __expf(sv[nt][r] - m_i[r]);
                sv[nt][r] = p;
                rs[r] += p;
            }
#pragma unroll
        for (int r = 0; r < 4; ++r) {
            float t2 = rs[r];
            t2 += __shfl_xor(t2, 1);
            t2 += __shfl_xor(t2, 2);
            t2 += __shfl_xor(t2, 4);
            t2 += __shfl_xor(t2, 8);
            l_i[r] = l_i[r] * alpha[r] + t2;
        }
#pragma unroll
        for (int nt = 0; nt < 4; ++nt)
#pragma unroll
            for (int r = 0; r < 4; ++r) oacc[nt][r] *= alpha[r];

#pragma unroll
        for (int nt = 0; nt < 4; ++nt)
#pragma unroll
            for (int r = 0; r < 4; ++r)
                myp[(quad * 4 + r) * 72 + nt * 16 + l16] = f2bf(sv[nt][r]);

#pragma unroll
        for (int kst = 0; kst < 2; ++kst) {
            BF8 ap;
            ap.u = *(const uint4*)(myp + l16 * 72 + kst * 32 + quad * 8);
#pragma unroll
            for (int nt = 0; nt < 4; ++nt) {
                BF8 bv;
                bv.u = *(const uint4*)(vT + (size_t)(b * 64 + nt * 16 + l16) * 2048 + j0 +
                                       kst * 32 + quad * 8);
                oacc[nt] = __builtin_amdgcn_mfma_f32_16x16x32_bf16(ap.v, bv.v, oacc[nt], 0, 0, 0);
            }
        }
    }

    const size_t ob = (size_t)id * 1024;
#pragma unroll
    for (int nt = 0; nt < 4; ++nt)
#pragma unroll
        for (int r = 0; r < 4; ++r)
            Opart[ob + (quad * 4 + r) * 64 + nt * 16 + l16] = oacc[nt][r];
    if (l16 == 0) {
#pragma unroll
        for (int r = 0; r < 4; ++r) {
            mpart[id * 16 + quad * 4 + r] = m_i[r];
            lpart[id * 16 + quad * 4 + r] = l_i[r];
        }
    }
}

// ---------------------------------------------------------------------------
// Kernel 3: merge. Grid 128 blocks x 256 thr; wave task qtid = blockIdx*4+w
// in [0,512): b=qtid>>7, qt=qtid&127. Lane owns col=lane for all 16 rows.
// ---------------------------------------------------------------------------
__global__ __launch_bounds__(256) void attn_merge(const float* __restrict__ Opart,
                                                  const float* __restrict__ mpart,
                                                  const float* __restrict__ lpart,
                                                  float* __restrict__ out) {
    const int tid = threadIdx.x;
    const int w = tid >> 6;
    const int lane = tid & 63;
    const int qtid = blockIdx.x * 4 + w;
    const int b = qtid >> 7;
    const int qt = qtid & 127;
    const int nc = (qt >> 4) + 1;
    const int base_id = b * 1024 + qt * 8;

    float M[16];
#pragma unroll
    for (int r = 0; r < 16; ++r) M[r] = -3.0e38f;
    for (int c = 0; c < nc; ++c)
#pragma unroll
        for (int r = 0; r < 16; ++r) M[r] = fmaxf(M[r], mpart[(base_id + c) * 16 + r]);

    float L[16], O[16];
#pragma unroll
    for (int r = 0; r < 16; ++r) { L[r] = 0.0f; O[r] = 0.0f; }
    for (int c = 0; c < nc; ++c) {
        const float* op = Opart + (size_t)(base_id + c) * 1024;
#pragma unroll
        for (int r = 0; r < 16; ++r) {
            float e = __expf(mpart[(base_id + c) * 16 + r] - M[r]);
            L[r] += e * lpart[(base_id + c) * 16 + r];
            O[r] += e * op[r * 64 + lane];
        }
    }
#pragma unroll
    for (int r = 0; r < 16; ++r)
        out[(size_t)(b * 2048 + qt * 16 + r) * 64 + lane] = O[r] / L[r];
}

extern "C" void kernel_launch(void* const* d_in, const int* in_sizes, int n_in,
                              void* d_out, int out_size, void* d_ws, size_t ws_size,
                              hipStream_t stream) {
    const float* x = (const float*)d_in[0];
    const float* Wq = (const float*)d_in[1];
    const float* Wk = (const float*)d_in[2];
    const float* Wv = (const float*)d_in[3];
    float* out = (float*)d_out;

    char* ws = (char*)d_ws;
    unsigned short* wt = (unsigned short*)(ws);
    unsigned short* q = (unsigned short*)(ws + 393216);
    unsigned short* k = (unsigned short*)(ws + 1441792);
    unsigned short* vT = (unsigned short*)(ws + 2490368);
    float* Opart = (float*)(ws + 3538944);
    float* mpart = (float*)(ws + 20316160ull);
    float* lpart = (float*)(ws + 20578304ull);

    hipLaunchKernelGGL(wt_kernel, dim3(768), dim3(256), 0, stream, Wq, Wk, Wv, wt);
    hipLaunchKernelGGL(qkv_kernel, dim3(512), dim3(256), 0, stream, x, wt, q, k, vT);
    hipLaunchKernelGGL(attn_partial, dim3(1024), dim3(256), 0, stream, q, k, vT, Opart, mpart, lpart);
    hipLaunchKernelGGL(attn_merge, dim3(128), dim3(256), 0, stream, Opart, mpart, lpart, out);
}